// Round 1
// baseline (1231.832 us; speedup 1.0000x reference)
//
#include <hip/hip_runtime.h>
#include <hip/hip_bf16.h>
#include <cmath>

typedef __attribute__((ext_vector_type(8))) short bf16x8;
typedef __attribute__((ext_vector_type(4))) float f32x4;

__device__ __forceinline__ float bf2f(unsigned short u) {
    unsigned int x = ((unsigned int)u) << 16;
    return __builtin_bit_cast(float, x);
}
__device__ __forceinline__ unsigned short f2bf(float f) {
    unsigned int x = __builtin_bit_cast(unsigned int, f);
    unsigned int lsb = (x >> 16) & 1u;
    x += 0x7fffu + lsb;
    return (unsigned short)(x >> 16);
}
__device__ __forceinline__ float sigm(float z) {
    return 1.f / (1.f + __expf(-z));
}

// ---------------------------------------------------------------------------
// prep_M: M = WQ1^T @ WK1  (256x256), written bf16 in MFMA B-fragment order:
// M_pk[((nb*8+kb)*64 + lane)*8 + j] = M[kb*32 + (lane>>4)*8 + j][nb*16 + (lane&15)]
// ---------------------------------------------------------------------------
__global__ void __launch_bounds__(256) prep_M(const float* __restrict__ WQ1,
                                              const float* __restrict__ WK1,
                                              unsigned short* __restrict__ M_pk) {
    __shared__ unsigned short As[256][32];
    __shared__ unsigned short Bs[256][32];
    int bx = blockIdx.x;
    int e0 = (bx >> 3) << 5;
    int f0 = (bx & 7) << 5;
    int tid = threadIdx.x;
    int col = tid & 31, rr = tid >> 5;
    for (int rep = 0; rep < 32; ++rep) {
        int d = rep * 8 + rr;
        As[d][col] = f2bf(WQ1[d * 256 + e0 + col]);
        Bs[d][col] = f2bf(WK1[d * 256 + f0 + col]);
    }
    __syncthreads();
    int el = tid & 31;
    int fl0 = tid >> 5;
    for (int i = 0; i < 4; ++i) {
        int fl = fl0 + 8 * i;
        float acc = 0.f;
        for (int d = 0; d < 256; ++d)
            acc += bf2f(As[d][el]) * bf2f(Bs[d][fl]);
        int e = e0 + el, f = f0 + fl;
        int kb = e >> 5, r = (e >> 3) & 3, j = e & 7;
        int nb = f >> 4;
        int lane = (r << 4) | (f & 15);
        M_pk[(((nb * 8 + kb) * 64) + lane) * 8 + j] = f2bf(acc);
    }
}

// ---------------------------------------------------------------------------
// prep_WT: WihT[k*1024+g] = Wih1[g*256+k]; block 1024 computes alpha cumprod.
// ---------------------------------------------------------------------------
__global__ void __launch_bounds__(256) prep_WT(const float* __restrict__ Wih,
                                               float* __restrict__ WihT,
                                               const float* __restrict__ betas,
                                               const int* __restrict__ dift,
                                               float* __restrict__ alpha) {
    if (blockIdx.x == 1024) {
        int tid = threadIdx.x;
        if (tid < 32) {
            int tb = dift[tid];
            float p = 1.f;
            for (int i = 0; i <= tb; ++i) p *= (1.f - betas[i]);
            alpha[tid] = p;
        }
        return;
    }
    int idx = blockIdx.x * 256 + threadIdx.x;
    int k = idx >> 10, g = idx & 1023;
    WihT[idx] = Wih[g * 256 + k];
}

// ---------------------------------------------------------------------------
// attn_bags: per (b,v) bag: x=emb[tok] (32x256); t1=x@M; dp=t1@x^T;
// softmax((dp-cm_c-cm_e)/16); w = (gate*femb_factor)^T @ sp; vv = w @ x.
// One 256-thread block per bag, bf16 MFMA 16x16x32, XOR-swizzled LDS.
// ---------------------------------------------------------------------------
__global__ void __launch_bounds__(256) attn_bags(
    const int* __restrict__ seqs, const float* __restrict__ tstep,
    const float* __restrict__ cmask, const float* __restrict__ emb,
    const float* __restrict__ decay, const float* __restrict__ initial,
    const unsigned short* __restrict__ M_pk, float* __restrict__ vv) {
    __shared__ __align__(16) unsigned short x_bf[32 * 256];
    __shared__ __align__(16) unsigned short t1_bf[32 * 256];
    __shared__ float dp_f[32 * 33];
    __shared__ float gate_sh[32];
    __shared__ float cm_sh[32];
    __shared__ int tok_sh[32];
    __shared__ float w_sh[32];

    int bag = blockIdx.x;
    int tid = threadIdx.x;

    if (tid < 32) {
        int tok = seqs[bag * 32 + tid];
        tok_sh[tid] = tok;
        float cm = cmask[bag * 32 + tid];
        cm_sh[tid] = cm;
        float tt = tstep[bag];
        float g = sigm(decay[tok] * tt + initial[tok]);
        g *= (cm - 1e20f) / (-1e20f);   // femb scale factor, exact for cm=0
        gate_sh[tid] = g;
    }
    __syncthreads();

    // stage x rows as bf16, row-XOR swizzle (elem col ^ ((row&7)<<3))
    for (int it = 0; it < 8; ++it) {
        int fidx = it * 256 + tid;
        int c = fidx >> 6;
        int f4 = fidx & 63;
        const float4* src = reinterpret_cast<const float4*>(emb + (size_t)tok_sh[c] * 256) + f4;
        float4 vx = *src;
        int colx = f4 * 4;
        int eidx = c * 256 + (colx ^ ((c & 7) << 3));
        ushort4 w;
        w.x = f2bf(vx.x); w.y = f2bf(vx.y); w.z = f2bf(vx.z); w.w = f2bf(vx.w);
        *reinterpret_cast<ushort4*>(&x_bf[eidx]) = w;
    }
    __syncthreads();

    int wv = tid >> 6;
    int lane = tid & 63;
    int lr = lane & 15;
    int lk = lane >> 4;

    // t1 = x @ M : wave wv owns output cols [wv*64, wv*64+64)
    f32x4 acc[2][4];
    for (int a = 0; a < 2; ++a)
        for (int n = 0; n < 4; ++n) acc[a][n] = (f32x4){0.f, 0.f, 0.f, 0.f};
    for (int kb = 0; kb < 8; ++kb) {
        bf16x8 afr[2];
        for (int mb = 0; mb < 2; ++mb) {
            int row = mb * 16 + lr;
            int colx = kb * 32 + lk * 8;
            afr[mb] = *reinterpret_cast<const bf16x8*>(&x_bf[row * 256 + (colx ^ ((row & 7) << 3))]);
        }
        for (int nbi = 0; nbi < 4; ++nbi) {
            int nb = wv * 4 + nbi;
            bf16x8 bfr = *reinterpret_cast<const bf16x8*>(M_pk + (((nb * 8 + kb) * 64) + lane) * 8);
            acc[0][nbi] = __builtin_amdgcn_mfma_f32_16x16x32_bf16(afr[0], bfr, acc[0][nbi], 0, 0, 0);
            acc[1][nbi] = __builtin_amdgcn_mfma_f32_16x16x32_bf16(afr[1], bfr, acc[1][nbi], 0, 0, 0);
        }
    }
    for (int mb = 0; mb < 2; ++mb)
        for (int nbi = 0; nbi < 4; ++nbi)
            for (int r = 0; r < 4; ++r) {
                int row = mb * 16 + lk * 4 + r;
                int colx = wv * 64 + nbi * 16 + lr;
                t1_bf[row * 256 + (colx ^ ((row & 7) << 3))] = f2bf(acc[mb][nbi][r]);
            }
    __syncthreads();

    // dp = t1 @ x^T : wave -> (mb, nb) quadrant of 32x32
    {
        int mb = wv >> 1, nb2 = wv & 1;
        f32x4 dacc = (f32x4){0.f, 0.f, 0.f, 0.f};
        for (int kb = 0; kb < 8; ++kb) {
            int cola = kb * 32 + lk * 8;
            int rowa = mb * 16 + lr;
            bf16x8 afr = *reinterpret_cast<const bf16x8*>(&t1_bf[rowa * 256 + (cola ^ ((rowa & 7) << 3))]);
            int rowb = nb2 * 16 + lr;
            bf16x8 bfr = *reinterpret_cast<const bf16x8*>(&x_bf[rowb * 256 + (cola ^ ((rowb & 7) << 3))]);
            dacc = __builtin_amdgcn_mfma_f32_16x16x32_bf16(afr, bfr, dacc, 0, 0, 0);
        }
        for (int r = 0; r < 4; ++r) {
            int c = mb * 16 + lk * 4 + r;
            int e = nb2 * 16 + lr;
            dp_f[c * 33 + e] = dacc[r];
        }
    }
    __syncthreads();

    if (tid < 32) {  // row softmax
        int c = tid;
        float cmc = cm_sh[c];
        float lg[32];
        float mx = -1e30f;
        for (int e = 0; e < 32; ++e) {
            float l = (dp_f[c * 33 + e] - cmc - cm_sh[e]) * 0.0625f;
            lg[e] = l;
            mx = fmaxf(mx, l);
        }
        float s = 0.f;
        for (int e = 0; e < 32; ++e) { float ex = __expf(lg[e] - mx); lg[e] = ex; s += ex; }
        float inv = 1.f / s;
        for (int e = 0; e < 32; ++e) dp_f[c * 33 + e] = lg[e] * inv;
    }
    __syncthreads();
    if (tid < 32) {  // w[e] = sum_c gate[c]*sp[c][e]
        int e = tid;
        float a2 = 0.f;
        for (int c = 0; c < 32; ++c) a2 += gate_sh[c] * dp_f[c * 33 + e];
        w_sh[e] = a2;
    }
    __syncthreads();

    // vv[d] = sum_e w[e]*x[e][d]
    float accv = 0.f;
    int d = tid;
    for (int e = 0; e < 32; ++e)
        accv += w_sh[e] * bf2f(x_bf[e * 256 + (d ^ ((e & 7) << 3))]);
    vv[(size_t)bag * 256 + d] = accv;
}

// ---------------------------------------------------------------------------
// x1_gemm: X1[t][g][b] = vv[b*64+t] . Wih1[g] + lstm_b[g]
// block = 8 consecutive vv rows, threads cover g via 4 chunks of 256.
// ---------------------------------------------------------------------------
__global__ void __launch_bounds__(256) x1_gemm(const float* __restrict__ vv,
                                               const float* __restrict__ WihT,
                                               const float* __restrict__ lstm_b,
                                               float* __restrict__ X1) {
    __shared__ float vrow_s[8][256];
    int blk = blockIdx.x;  // 256 blocks, rows i = blk*8 .. blk*8+7
    int tid = threadIdx.x;
    for (int r = 0; r < 8; ++r)
        vrow_s[r][tid] = vv[(size_t)(blk * 8 + r) * 256 + tid];
    __syncthreads();
    float acc[8][4];
    for (int r = 0; r < 8; ++r)
        for (int q = 0; q < 4; ++q) acc[r][q] = lstm_b[q * 256 + tid];
    for (int k = 0; k < 256; ++k) {
        const float* wr = WihT + (size_t)k * 1024;
        float w0 = wr[tid], w1 = wr[256 + tid], w2 = wr[512 + tid], w3 = wr[768 + tid];
        for (int r = 0; r < 8; ++r) {
            float xv = vrow_s[r][k];
            acc[r][0] += xv * w0; acc[r][1] += xv * w1;
            acc[r][2] += xv * w2; acc[r][3] += xv * w3;
        }
    }
    for (int r = 0; r < 8; ++r) {
        int i = blk * 8 + r;
        int b = i >> 6, t = i & 63;
        float* xo = X1 + ((size_t)t * 1024) * 32;
        for (int q = 0; q < 4; ++q)
            xo[(size_t)(q * 256 + tid) * 32 + b] = acc[r][q];
    }
}

// ---------------------------------------------------------------------------
// lstm_step: launch t = 0..64. Blocks 0..31: LSTM1 step t (if t<64).
// Blocks 32..95: LSTM2 step t-1 (if t>=1). Layouts: X1[t][g][b],
// h*_all[t][d][b], c*[d][b]. lstm_b folded into X1; hs_b added here.
// ---------------------------------------------------------------------------
__global__ void __launch_bounds__(256) lstm_step(
    int t, const float* __restrict__ X1, const float* __restrict__ Whh1,
    const float* __restrict__ Wih2, const float* __restrict__ Whh2,
    const float* __restrict__ hs_b, float* __restrict__ h1_all,
    float* __restrict__ h2_all, float* __restrict__ c1, float* __restrict__ c2) {
    int blk = blockIdx.x;
    int tid = threadIdx.x;
    int b = tid & 31;
    int jl = tid >> 5;
    if (blk < 32) {
        if (t >= 64) return;
        int j = blk * 8 + jl;
        const float* xb = X1 + ((size_t)t * 1024) * 32 + b;
        float z0 = xb[(size_t)(0 * 256 + j) * 32];
        float z1 = xb[(size_t)(1 * 256 + j) * 32];
        float z2 = xb[(size_t)(2 * 256 + j) * 32];
        float z3 = xb[(size_t)(3 * 256 + j) * 32];
        float cprev = 0.f;
        if (t > 0) {
            const float* hb = h1_all + ((size_t)(t - 1) * 256) * 32 + b;
            const float* w0 = Whh1 + (size_t)(0 * 256 + j) * 256;
            const float* w1 = Whh1 + (size_t)(1 * 256 + j) * 256;
            const float* w2 = Whh1 + (size_t)(2 * 256 + j) * 256;
            const float* w3 = Whh1 + (size_t)(3 * 256 + j) * 256;
            for (int k = 0; k < 256; ++k) {
                float hv = hb[(size_t)k * 32];
                z0 += w0[k] * hv; z1 += w1[k] * hv;
                z2 += w2[k] * hv; z3 += w3[k] * hv;
            }
            cprev = c1[j * 32 + b];
        }
        float ig = sigm(z0), fg = sigm(z1), gg = tanhf(z2), og = sigm(z3);
        float cn = fg * cprev + ig * gg;
        float hn = og * tanhf(cn);
        c1[j * 32 + b] = cn;
        h1_all[((size_t)t * 256 + j) * 32 + b] = hn;
    } else {
        if (t < 1) return;
        __shared__ float red[4][8][32];
        int s = t - 1;
        int bl2 = blk - 32;
        int j = bl2 * 4 + (jl & 3);
        int half = jl >> 2;
        int k0 = half * 128;
        float z0 = 0.f, z1 = 0.f, z2 = 0.f, z3 = 0.f;
        {
            const float* h1b = h1_all + ((size_t)s * 256) * 32 + b;
            const float* w0 = Wih2 + (size_t)(0 * 256 + j) * 256;
            const float* w1 = Wih2 + (size_t)(1 * 256 + j) * 256;
            const float* w2 = Wih2 + (size_t)(2 * 256 + j) * 256;
            const float* w3 = Wih2 + (size_t)(3 * 256 + j) * 256;
            for (int k = k0; k < k0 + 128; ++k) {
                float hv = h1b[(size_t)k * 32];
                z0 += w0[k] * hv; z1 += w1[k] * hv;
                z2 += w2[k] * hv; z3 += w3[k] * hv;
            }
        }
        if (s > 0) {
            const float* h2b = h2_all + ((size_t)(s - 1) * 256) * 32 + b;
            const float* w0 = Whh2 + (size_t)(0 * 256 + j) * 256;
            const float* w1 = Whh2 + (size_t)(1 * 256 + j) * 256;
            const float* w2 = Whh2 + (size_t)(2 * 256 + j) * 256;
            const float* w3 = Whh2 + (size_t)(3 * 256 + j) * 256;
            for (int k = k0; k < k0 + 128; ++k) {
                float hv = h2b[(size_t)k * 32];
                z0 += w0[k] * hv; z1 += w1[k] * hv;
                z2 += w2[k] * hv; z3 += w3[k] * hv;
            }
        }
        red[0][jl][b] = z0; red[1][jl][b] = z1;
        red[2][jl][b] = z2; red[3][jl][b] = z3;
        __syncthreads();
        if (half == 0) {
            z0 = red[0][jl][b] + red[0][jl + 4][b] + hs_b[0 * 256 + j];
            z1 = red[1][jl][b] + red[1][jl + 4][b] + hs_b[1 * 256 + j];
            z2 = red[2][jl][b] + red[2][jl + 4][b] + hs_b[2 * 256 + j];
            z3 = red[3][jl][b] + red[3][jl + 4][b] + hs_b[3 * 256 + j];
            float ig = sigm(z0), fg = sigm(z1), gg = tanhf(z2), og = sigm(z3);
            float cprev = (s > 0) ? c2[j * 32 + b] : 0.f;
            float cn = fg * cprev + ig * gg;
            float hn = og * tanhf(cn);
            c2[j * 32 + b] = cn;
            h2_all[((size_t)s * 256 + j) * 32 + b] = hn;
        }
    }
}

// ---------------------------------------------------------------------------
// tail: per batch, only row v* = lengths[b]-1 matters.
// ---------------------------------------------------------------------------
__global__ void __launch_bounds__(256) tail_k(
    const int* __restrict__ lengths, const float* __restrict__ h1_all,
    const float* __restrict__ h2_all, const float* __restrict__ whk_W,
    const float* __restrict__ whk_b, const float* __restrict__ w1_W,
    const float* __restrict__ w1_b, const float* __restrict__ w2_W,
    const float* __restrict__ w2_b, const float* __restrict__ fuse_W,
    const float* __restrict__ fuse_b, const float* __restrict__ lab_W,
    const float* __restrict__ lab_b, const float* __restrict__ Wdiff,
    const float* __restrict__ alpha, const float* __restrict__ noise,
    float* __restrict__ out) {
    __shared__ float ek[256], tv[256], hs[256], whp[256], a1s[64];
    __shared__ float noisy_s[256], fin[512], fused_s[256], attn_s[2];
    int b = blockIdx.x, tid = threadIdx.x;
    int vstar = lengths[b] - 1;
    ek[tid] = h1_all[(size_t)tid * 32 + b];
    tv[tid] = h1_all[((size_t)vstar * 256 + tid) * 32 + b];
    if (vstar > 0) hs[tid] = h2_all[((size_t)(vstar - 1) * 256 + tid) * 32 + b];
    __syncthreads();

    float aligned;
    if (vstar > 0) {
        float acc = whk_b[tid];
        const float* wr = whk_W + (size_t)tid * 256;
        for (int k = 0; k < 256; ++k) acc += wr[k] * hs[k];
        whp[tid] = acc;
        __syncthreads();
        if (tid < 64) {
            float a2 = w1_b[tid];
            const float* wr1 = w1_W + (size_t)tid * 512;
            for (int k = 0; k < 256; ++k) a2 += wr1[k] * ek[k];
            for (int k = 0; k < 256; ++k) a2 += wr1[256 + k] * whp[k];
            a1s[tid] = tanhf(a2);
        }
        __syncthreads();
        if (tid < 2) {
            float a3 = w2_b[tid];
            const float* wr2 = w2_W + tid * 64;
            for (int k = 0; k < 64; ++k) a3 += wr2[k] * a1s[k];
            attn_s[tid] = a3;
        }
        __syncthreads();
        float m = fmaxf(attn_s[0], attn_s[1]);
        float e0 = __expf(attn_s[0] - m), e1 = __expf(attn_s[1] - m);
        float inv = 1.f / (e0 + e1);
        aligned = ek[tid] * (e0 * inv) + whp[tid] * (e1 * inv);
    } else {
        aligned = ek[tid];
    }

    float al = alpha[b];
    float sa = sqrtf(al), sb = sqrtf(1.f - al);
    float nz = noise[((size_t)b * 64 + vstar) * 256 + tid];
    noisy_s[tid] = aligned * sa + nz * sb;
    __syncthreads();
    float pn = 0.f;
    for (int k = 0; k < 256; ++k) pn += noisy_s[k] * Wdiff[(size_t)k * 256 + tid];
    float gen = aligned + nz - pn;
    fin[tid] = tv[tid];
    fin[256 + tid] = gen;
    __syncthreads();
    float fu = fuse_b[tid];
    const float* fw = fuse_W + (size_t)tid * 512;
    for (int k = 0; k < 512; ++k) fu += fw[k] * fin[k];
    fused_s[tid] = fu;
    __syncthreads();
    if (tid < 2) {
        float o = lab_b[tid];
        const float* lw = lab_W + tid * 256;
        for (int k = 0; k < 256; ++k) o += lw[k] * fused_s[k];
        out[b * 2 + tid] = o;
    }
}

// ---------------------------------------------------------------------------
extern "C" void kernel_launch(void* const* d_in, const int* in_sizes, int n_in,
                              void* d_out, int out_size, void* d_ws, size_t ws_size,
                              hipStream_t stream) {
    const int*   seqs    = (const int*)  d_in[0];
    const int*   lengths = (const int*)  d_in[2];
    const float* tstep   = (const float*)d_in[3];
    const float* cmask   = (const float*)d_in[4];
    const float* emb     = (const float*)d_in[5];
    const float* WQ1     = (const float*)d_in[6];
    const float* WK1     = (const float*)d_in[7];
    const float* decay   = (const float*)d_in[8];
    const float* initial = (const float*)d_in[9];
    const float* Wih1    = (const float*)d_in[10];
    const float* Whh1    = (const float*)d_in[11];
    const float* lstm_b  = (const float*)d_in[12];
    const float* Wih2    = (const float*)d_in[13];
    const float* Whh2    = (const float*)d_in[14];
    const float* hs_b    = (const float*)d_in[15];
    const float* whk_W   = (const float*)d_in[16];
    const float* whk_b   = (const float*)d_in[17];
    const float* w1_W    = (const float*)d_in[18];
    const float* w1_b    = (const float*)d_in[19];
    const float* w2_W    = (const float*)d_in[20];
    const float* w2_b    = (const float*)d_in[21];
    const float* fuse_W  = (const float*)d_in[22];
    const float* fuse_b  = (const float*)d_in[23];
    const float* lab_W   = (const float*)d_in[24];
    const float* lab_b   = (const float*)d_in[25];
    const float* betas   = (const float*)d_in[26];
    const float* Wdiff   = (const float*)d_in[27];
    const int*   dift    = (const int*)  d_in[28];
    const float* noise   = (const float*)d_in[29];
    float* out = (float*)d_out;

    float* ws = (float*)d_ws;
    unsigned short* M_pk = (unsigned short*)ws;   // 65536 u16  (32768 floats)
    float* alpha  = ws + 32768;                   // 32 (+pad)
    float* WihT   = ws + 32832;                   // 262144
    float* vv     = WihT + 262144;                // 524288
    float* X1     = vv + 524288;                  // 2097152
    float* h1_all = X1 + 2097152;                 // 524288
    float* h2_all = h1_all + 524288;              // 524288
    float* c1     = h2_all + 524288;              // 8192
    float* c2     = c1 + 8192;                    // 8192  => ~15.2 MB total

    prep_M<<<64, 256, 0, stream>>>(WQ1, WK1, M_pk);
    prep_WT<<<1025, 256, 0, stream>>>(Wih1, WihT, betas, dift, alpha);
    attn_bags<<<2048, 256, 0, stream>>>(seqs, tstep, cmask, emb, decay, initial, M_pk, vv);
    x1_gemm<<<256, 256, 0, stream>>>(vv, WihT, lstm_b, X1);
    for (int t = 0; t <= 64; ++t)
        lstm_step<<<96, 256, 0, stream>>>(t, X1, Whh1, Wih2, Whh2, hs_b,
                                          h1_all, h2_all, c1, c2);
    tail_k<<<32, 256, 0, stream>>>(lengths, h1_all, h2_all, whk_W, whk_b,
                                   w1_W, w1_b, w2_W, w2_b, fuse_W, fuse_b,
                                   lab_W, lab_b, Wdiff, alpha, noise, out);
}

// Round 2
// 905.565 us; speedup vs baseline: 1.3603x; 1.3603x over previous
//
#include <hip/hip_runtime.h>
#include <hip/hip_bf16.h>
#include <cmath>

typedef __attribute__((ext_vector_type(8))) short bf16x8;
typedef __attribute__((ext_vector_type(4))) float f32x4;

#define NWG_LSTM 48

__device__ __forceinline__ float bf2f(unsigned short u) {
    unsigned int x = ((unsigned int)u) << 16;
    return __builtin_bit_cast(float, x);
}
__device__ __forceinline__ unsigned short f2bf(float f) {
    unsigned int x = __builtin_bit_cast(unsigned int, f);
    unsigned int lsb = (x >> 16) & 1u;
    x += 0x7fffu + lsb;
    return (unsigned short)(x >> 16);
}
__device__ __forceinline__ float sigm(float z) {
    return 1.f / (1.f + __expf(-z));
}

// ---------------------------------------------------------------------------
// prep_M: M = WQ1^T @ WK1  (256x256), bf16 in MFMA B-fragment order.
// ---------------------------------------------------------------------------
__global__ void __launch_bounds__(256) prep_M(const float* __restrict__ WQ1,
                                              const float* __restrict__ WK1,
                                              unsigned short* __restrict__ M_pk) {
    __shared__ unsigned short As[256][32];
    __shared__ unsigned short Bs[256][32];
    int bx = blockIdx.x;
    int e0 = (bx >> 3) << 5;
    int f0 = (bx & 7) << 5;
    int tid = threadIdx.x;
    int col = tid & 31, rr = tid >> 5;
    for (int rep = 0; rep < 32; ++rep) {
        int d = rep * 8 + rr;
        As[d][col] = f2bf(WQ1[d * 256 + e0 + col]);
        Bs[d][col] = f2bf(WK1[d * 256 + f0 + col]);
    }
    __syncthreads();
    int el = tid & 31;
    int fl0 = tid >> 5;
    for (int i = 0; i < 4; ++i) {
        int fl = fl0 + 8 * i;
        float acc = 0.f;
        for (int d = 0; d < 256; ++d)
            acc += bf2f(As[d][el]) * bf2f(Bs[d][fl]);
        int e = e0 + el, f = f0 + fl;
        int kb = e >> 5, r = (e >> 3) & 3, j = e & 7;
        int nb = f >> 4;
        int lane = (r << 4) | (f & 15);
        M_pk[(((nb * 8 + kb) * 64) + lane) * 8 + j] = f2bf(acc);
    }
}

// ---------------------------------------------------------------------------
// pack_rec: pack Whh1/Wih2/Whh2 into per-wg bf16 hi/lo fragment streams.
// Stream: elem[(((w*32 + i)*64 + lane)*8 + j]. Block 384 zeroes barrier.
//   A (w<16):  d0=w*16;  i = nt*8+kb;  row = nt*256 + d0 + (lane&15)
//   B (w>=16): d0=(w-16)*8; i = (mat*2+nt2)*8+kb;
//              row = (nt2*2 + (cl>>3))*256 + d0 + (cl&7)
// ---------------------------------------------------------------------------
__global__ void __launch_bounds__(256) pack_rec(const float* __restrict__ Whh1,
                                                const float* __restrict__ Wih2,
                                                const float* __restrict__ Whh2,
                                                unsigned short* __restrict__ Wpk_hi,
                                                unsigned short* __restrict__ Wpk_lo,
                                                int* __restrict__ bar) {
    if (blockIdx.x == 384) {
        if (threadIdx.x < 128) bar[threadIdx.x] = 0;
        return;
    }
    int c = blockIdx.x * 256 + threadIdx.x;      // chunk id, 98304 total
    int w = c >> 11;
    int r = c & 2047;
    int i = r >> 6;
    int lane = r & 63;
    int cl = lane & 15, kh = lane >> 4;
    const float* src;
    int grow, k0;
    if (w < 16) {
        int d0 = w * 16;
        int nt = i >> 3, kb = i & 7;
        grow = nt * 256 + d0 + cl;
        k0 = kb * 32 + kh * 8;
        src = Whh1;
    } else {
        int d0 = (w - 16) * 8;
        int mat = i >> 4;
        int ii = i & 15;
        int nt2 = ii >> 3, kb = ii & 7;
        grow = (nt2 * 2 + (cl >> 3)) * 256 + d0 + (cl & 7);
        k0 = kb * 32 + kh * 8;
        src = mat ? Whh2 : Wih2;
    }
    const float* sp = src + (size_t)grow * 256 + k0;
    bf16x8 hi, lo;
    for (int j = 0; j < 8; ++j) {
        float v = sp[j];
        unsigned short h = f2bf(v);
        hi[j] = (short)h;
        lo[j] = (short)f2bf(v - bf2f(h));
    }
    size_t o = (size_t)c * 8;
    *reinterpret_cast<bf16x8*>(Wpk_hi + o) = hi;
    *reinterpret_cast<bf16x8*>(Wpk_lo + o) = lo;
}

// ---------------------------------------------------------------------------
// pack_w1: Wih1 -> bf16 hi/lo fragment stream [nt(64)][kb(8)][lane][8].
// Block 128 computes alpha cumprod.
// ---------------------------------------------------------------------------
__global__ void __launch_bounds__(256) pack_w1(const float* __restrict__ Wih1,
                                               unsigned short* __restrict__ W1h,
                                               unsigned short* __restrict__ W1l,
                                               const float* __restrict__ betas,
                                               const int* __restrict__ dift,
                                               float* __restrict__ alpha) {
    if (blockIdx.x == 128) {
        int tid = threadIdx.x;
        if (tid < 32) {
            int tb = dift[tid];
            float p = 1.f;
            for (int i = 0; i <= tb; ++i) p *= (1.f - betas[i]);
            alpha[tid] = p;
        }
        return;
    }
    int c = blockIdx.x * 256 + threadIdx.x;      // 32768 chunks
    int nt = c >> 9;
    int r = c & 511;
    int kb = r >> 6;
    int lane = r & 63;
    int grow = nt * 16 + (lane & 15);
    int k0 = kb * 32 + (lane >> 4) * 8;
    const float* sp = Wih1 + (size_t)grow * 256 + k0;
    bf16x8 hi, lo;
    for (int j = 0; j < 8; ++j) {
        float v = sp[j];
        unsigned short h = f2bf(v);
        hi[j] = (short)h;
        lo[j] = (short)f2bf(v - bf2f(h));
    }
    size_t o = (size_t)c * 8;
    *reinterpret_cast<bf16x8*>(W1h + o) = hi;
    *reinterpret_cast<bf16x8*>(W1l + o) = lo;
}

// ---------------------------------------------------------------------------
// attn_bags (unchanged from R1, passed correctness)
// ---------------------------------------------------------------------------
__global__ void __launch_bounds__(256) attn_bags(
    const int* __restrict__ seqs, const float* __restrict__ tstep,
    const float* __restrict__ cmask, const float* __restrict__ emb,
    const float* __restrict__ decay, const float* __restrict__ initial,
    const unsigned short* __restrict__ M_pk, float* __restrict__ vv) {
    __shared__ __align__(16) unsigned short x_bf[32 * 256];
    __shared__ __align__(16) unsigned short t1_bf[32 * 256];
    __shared__ float dp_f[32 * 33];
    __shared__ float gate_sh[32];
    __shared__ float cm_sh[32];
    __shared__ int tok_sh[32];
    __shared__ float w_sh[32];

    int bag = blockIdx.x;
    int tid = threadIdx.x;

    if (tid < 32) {
        int tok = seqs[bag * 32 + tid];
        tok_sh[tid] = tok;
        float cm = cmask[bag * 32 + tid];
        cm_sh[tid] = cm;
        float tt = tstep[bag];
        float g = sigm(decay[tok] * tt + initial[tok]);
        g *= (cm - 1e20f) / (-1e20f);
        gate_sh[tid] = g;
    }
    __syncthreads();

    for (int it = 0; it < 8; ++it) {
        int fidx = it * 256 + tid;
        int c = fidx >> 6;
        int f4 = fidx & 63;
        const float4* src = reinterpret_cast<const float4*>(emb + (size_t)tok_sh[c] * 256) + f4;
        float4 vx = *src;
        int colx = f4 * 4;
        int eidx = c * 256 + (colx ^ ((c & 7) << 3));
        ushort4 w;
        w.x = f2bf(vx.x); w.y = f2bf(vx.y); w.z = f2bf(vx.z); w.w = f2bf(vx.w);
        *reinterpret_cast<ushort4*>(&x_bf[eidx]) = w;
    }
    __syncthreads();

    int wv = tid >> 6;
    int lane = tid & 63;
    int lr = lane & 15;
    int lk = lane >> 4;

    f32x4 acc[2][4];
    for (int a = 0; a < 2; ++a)
        for (int n = 0; n < 4; ++n) acc[a][n] = (f32x4){0.f, 0.f, 0.f, 0.f};
    for (int kb = 0; kb < 8; ++kb) {
        bf16x8 afr[2];
        for (int mb = 0; mb < 2; ++mb) {
            int row = mb * 16 + lr;
            int colx = kb * 32 + lk * 8;
            afr[mb] = *reinterpret_cast<const bf16x8*>(&x_bf[row * 256 + (colx ^ ((row & 7) << 3))]);
        }
        for (int nbi = 0; nbi < 4; ++nbi) {
            int nb = wv * 4 + nbi;
            bf16x8 bfr = *reinterpret_cast<const bf16x8*>(M_pk + (((nb * 8 + kb) * 64) + lane) * 8);
            acc[0][nbi] = __builtin_amdgcn_mfma_f32_16x16x32_bf16(afr[0], bfr, acc[0][nbi], 0, 0, 0);
            acc[1][nbi] = __builtin_amdgcn_mfma_f32_16x16x32_bf16(afr[1], bfr, acc[1][nbi], 0, 0, 0);
        }
    }
    for (int mb = 0; mb < 2; ++mb)
        for (int nbi = 0; nbi < 4; ++nbi)
            for (int r = 0; r < 4; ++r) {
                int row = mb * 16 + lk * 4 + r;
                int colx = wv * 64 + nbi * 16 + lr;
                t1_bf[row * 256 + (colx ^ ((row & 7) << 3))] = f2bf(acc[mb][nbi][r]);
            }
    __syncthreads();

    {
        int mb = wv >> 1, nb2 = wv & 1;
        f32x4 dacc = (f32x4){0.f, 0.f, 0.f, 0.f};
        for (int kb = 0; kb < 8; ++kb) {
            int cola = kb * 32 + lk * 8;
            int rowa = mb * 16 + lr;
            bf16x8 afr = *reinterpret_cast<const bf16x8*>(&t1_bf[rowa * 256 + (cola ^ ((rowa & 7) << 3))]);
            int rowb = nb2 * 16 + lr;
            bf16x8 bfr = *reinterpret_cast<const bf16x8*>(&x_bf[rowb * 256 + (cola ^ ((rowb & 7) << 3))]);
            dacc = __builtin_amdgcn_mfma_f32_16x16x32_bf16(afr, bfr, dacc, 0, 0, 0);
        }
        for (int r = 0; r < 4; ++r) {
            int c = mb * 16 + lk * 4 + r;
            int e = nb2 * 16 + lr;
            dp_f[c * 33 + e] = dacc[r];
        }
    }
    __syncthreads();

    if (tid < 32) {
        int c = tid;
        float cmc = cm_sh[c];
        float lg[32];
        float mx = -1e30f;
        for (int e = 0; e < 32; ++e) {
            float l = (dp_f[c * 33 + e] - cmc - cm_sh[e]) * 0.0625f;
            lg[e] = l;
            mx = fmaxf(mx, l);
        }
        float s = 0.f;
        for (int e = 0; e < 32; ++e) { float ex = __expf(lg[e] - mx); lg[e] = ex; s += ex; }
        float inv = 1.f / s;
        for (int e = 0; e < 32; ++e) dp_f[c * 33 + e] = lg[e] * inv;
    }
    __syncthreads();
    if (tid < 32) {
        int e = tid;
        float a2 = 0.f;
        for (int c = 0; c < 32; ++c) a2 += gate_sh[c] * dp_f[c * 33 + e];
        w_sh[e] = a2;
    }
    __syncthreads();

    float accv = 0.f;
    int d = tid;
    for (int e = 0; e < 32; ++e)
        accv += w_sh[e] * bf2f(x_bf[e * 256 + (d ^ ((e & 7) << 3))]);
    vv[(size_t)bag * 256 + d] = accv;
}

// ---------------------------------------------------------------------------
// x1_mfma: X1bf[t][g][b] = bf16( vv @ Wih1^T + lstm_b ), split-bf16 MFMA.
// 512 blocks: rb (64, 32 vv-rows each) x gb (8, 128 g each).
// ---------------------------------------------------------------------------
__global__ void __launch_bounds__(256) x1_mfma(const float* __restrict__ vv,
                                               const unsigned short* __restrict__ W1h,
                                               const unsigned short* __restrict__ W1l,
                                               const float* __restrict__ lstm_b,
                                               unsigned short* __restrict__ X1bf) {
    __shared__ __align__(16) unsigned short xs[32 * 256];
    int blk = blockIdx.x;
    int rb = blk >> 3, gb = blk & 7;
    int tid = threadIdx.x;
    for (int it = 0; it < 8; ++it) {
        int idx = it * 256 + tid;
        int row = idx >> 6, f4 = idx & 63;
        float4 v = *reinterpret_cast<const float4*>(vv + (size_t)(rb * 32 + row) * 256 + f4 * 4);
        ushort4 w;
        w.x = f2bf(v.x); w.y = f2bf(v.y); w.z = f2bf(v.z); w.w = f2bf(v.w);
        *reinterpret_cast<ushort4*>(&xs[row * 256 + ((f4 * 4) ^ ((row & 7) << 3))]) = w;
    }
    __syncthreads();
    int wv = tid >> 6, lane = tid & 63, cl = lane & 15, kh = lane >> 4;
    f32x4 acc[2][2];
    for (int n = 0; n < 2; ++n) {
        int nt = gb * 8 + wv * 2 + n;
        float bz = lstm_b[nt * 16 + cl];
        acc[n][0] = (f32x4){bz, bz, bz, bz};
        acc[n][1] = (f32x4){bz, bz, bz, bz};
    }
    #pragma unroll
    for (int kb = 0; kb < 8; ++kb) {
        int k = kb * 32 + kh * 8;
        bf16x8 a0 = *reinterpret_cast<const bf16x8*>(&xs[cl * 256 + (k ^ ((cl & 7) << 3))]);
        bf16x8 a1 = *reinterpret_cast<const bf16x8*>(&xs[(16 + cl) * 256 + (k ^ (((16 + cl) & 7) << 3))]);
        for (int n = 0; n < 2; ++n) {
            int nt = gb * 8 + wv * 2 + n;
            size_t o = ((size_t)(nt * 8 + kb) * 64 + lane) * 8;
            bf16x8 bh = *reinterpret_cast<const bf16x8*>(W1h + o);
            bf16x8 bl = *reinterpret_cast<const bf16x8*>(W1l + o);
            acc[n][0] = __builtin_amdgcn_mfma_f32_16x16x32_bf16(a0, bh, acc[n][0], 0, 0, 0);
            acc[n][0] = __builtin_amdgcn_mfma_f32_16x16x32_bf16(a0, bl, acc[n][0], 0, 0, 0);
            acc[n][1] = __builtin_amdgcn_mfma_f32_16x16x32_bf16(a1, bh, acc[n][1], 0, 0, 0);
            acc[n][1] = __builtin_amdgcn_mfma_f32_16x16x32_bf16(a1, bl, acc[n][1], 0, 0, 0);
        }
    }
    for (int n = 0; n < 2; ++n) {
        int nt = gb * 8 + wv * 2 + n;
        int g = nt * 16 + cl;
        for (int mt = 0; mt < 2; ++mt)
            for (int r = 0; r < 4; ++r) {
                int row = rb * 32 + mt * 16 + kh * 4 + r;
                int b = row >> 6, t = row & 63;
                X1bf[((size_t)t * 1024 + g) * 32 + b] = f2bf(acc[n][mt][r]);
            }
    }
}

// ---------------------------------------------------------------------------
// lstm_persist: both LSTMs, 48 wgs, software grid barrier per step.
// wgs 0..15 (A): LSTM1, d-slice 16. wgs 16..47 (B): LSTM2, d-slice 8.
// Weights live in VGPRs (bf16 hi/lo); 3-product split-bf16 MFMA.
// h layout: h[t][b][d] bf16 hi/lo.
// ---------------------------------------------------------------------------
__device__ __forceinline__ void gridbar(int* bar, int p, int tid) {
    __syncthreads();
    if (tid == 0) {
        __threadfence();
        atomicAdd(&bar[p], 1);
        while (__hip_atomic_load(&bar[p], __ATOMIC_RELAXED, __HIP_MEMORY_SCOPE_AGENT) < NWG_LSTM)
            __builtin_amdgcn_s_sleep(2);
    }
    __syncthreads();
    __threadfence();
}

__global__ void __launch_bounds__(256, 1) lstm_persist(
    const unsigned short* __restrict__ Wpk_hi, const unsigned short* __restrict__ Wpk_lo,
    const unsigned short* __restrict__ X1bf, const float* __restrict__ hs_b,
    unsigned short* h1hi, unsigned short* h1lo,
    unsigned short* h2hi, unsigned short* h2lo,
    int* bar) {
    __shared__ float zbuf[4][16][33];
    int wg = blockIdx.x, tid = threadIdx.x;
    int wv = tid >> 6, lane = tid & 63, cl = lane & 15, kh = lane >> 4;
    bool isA = wg < 16;
    int d0 = isA ? wg * 16 : (wg - 16) * 8;

    bf16x8 wh[8], wl[8];
    #pragma unroll
    for (int kb = 0; kb < 8; ++kb) {
        size_t o = ((size_t)(wg * 32 + wv * 8 + kb) * 64 + lane) * 8;
        wh[kb] = *reinterpret_cast<const bf16x8*>(Wpk_hi + o);
        wl[kb] = *reinterpret_cast<const bf16x8*>(Wpk_lo + o);
    }

    float cst0 = 0.f, cst1 = 0.f;
    float bias0 = 0.f, bias1 = 0.f, bias2 = 0.f, bias3 = 0.f;
    int dr_r = tid >> 5;   // recombine d index (0..7)
    int b_r  = tid & 31;   // recombine batch index
    if (!isA) {
        bias0 = hs_b[0 * 256 + d0 + dr_r];
        bias1 = hs_b[1 * 256 + d0 + dr_r];
        bias2 = hs_b[2 * 256 + d0 + dr_r];
        bias3 = hs_b[3 * 256 + d0 + dr_r];
    }

    for (int p = 0; p <= 64; ++p) {
        if (isA) {
            if (p < 64) {
                f32x4 acc0 = (f32x4){0.f, 0.f, 0.f, 0.f};
                f32x4 acc1 = acc0;
                if (p > 0) {
                    const unsigned short* hB = h1hi + (size_t)(p - 1) * 8192;
                    const unsigned short* lB = h1lo + (size_t)(p - 1) * 8192;
                    #pragma unroll
                    for (int kb = 0; kb < 8; ++kb) {
                        int k = kb * 32 + kh * 8;
                        bf16x8 a0h = *reinterpret_cast<const bf16x8*>(hB + cl * 256 + k);
                        bf16x8 a1h = *reinterpret_cast<const bf16x8*>(hB + (16 + cl) * 256 + k);
                        bf16x8 a0l = *reinterpret_cast<const bf16x8*>(lB + cl * 256 + k);
                        bf16x8 a1l = *reinterpret_cast<const bf16x8*>(lB + (16 + cl) * 256 + k);
                        acc0 = __builtin_amdgcn_mfma_f32_16x16x32_bf16(a0h, wh[kb], acc0, 0, 0, 0);
                        acc0 = __builtin_amdgcn_mfma_f32_16x16x32_bf16(a0l, wh[kb], acc0, 0, 0, 0);
                        acc0 = __builtin_amdgcn_mfma_f32_16x16x32_bf16(a0h, wl[kb], acc0, 0, 0, 0);
                        acc1 = __builtin_amdgcn_mfma_f32_16x16x32_bf16(a1h, wh[kb], acc1, 0, 0, 0);
                        acc1 = __builtin_amdgcn_mfma_f32_16x16x32_bf16(a1l, wh[kb], acc1, 0, 0, 0);
                        acc1 = __builtin_amdgcn_mfma_f32_16x16x32_bf16(a1h, wl[kb], acc1, 0, 0, 0);
                    }
                }
                for (int r = 0; r < 4; ++r) {
                    zbuf[wv][cl][kh * 4 + r] = acc0[r];
                    zbuf[wv][cl][16 + kh * 4 + r] = acc1[r];
                }
                __syncthreads();
                #pragma unroll
                for (int dd = 0; dd < 2; ++dd) {
                    int dr = dr_r + dd * 8;
                    size_t xb = ((size_t)p * 1024 + d0 + dr) * 32 + b_r;
                    float zi = zbuf[0][dr][b_r] + bf2f(X1bf[xb]);
                    float zf = zbuf[1][dr][b_r] + bf2f(X1bf[xb + 8192]);
                    float zg = zbuf[2][dr][b_r] + bf2f(X1bf[xb + 16384]);
                    float zo = zbuf[3][dr][b_r] + bf2f(X1bf[xb + 24576]);
                    float cold = dd ? cst1 : cst0;
                    float cn = sigm(zf) * cold + sigm(zi) * tanhf(zg);
                    float hn = sigm(zo) * tanhf(cn);
                    if (dd) cst1 = cn; else cst0 = cn;
                    unsigned short hv = f2bf(hn);
                    unsigned short lv = f2bf(hn - bf2f(hv));
                    size_t ho = ((size_t)p * 32 + b_r) * 256 + d0 + dr;
                    h1hi[ho] = hv;
                    h1lo[ho] = lv;
                }
            }
        } else {
            if (p >= 1) {
                int s = p - 1;
                int mat = wv >> 1;
                f32x4 acc0 = (f32x4){0.f, 0.f, 0.f, 0.f};
                f32x4 acc1 = acc0;
                bool active = (mat == 0) || (s > 0);
                if (active) {
                    const unsigned short* hB =
                        (mat == 0) ? (h1hi + (size_t)s * 8192) : (h2hi + (size_t)(s - 1) * 8192);
                    const unsigned short* lB =
                        (mat == 0) ? (h1lo + (size_t)s * 8192) : (h2lo + (size_t)(s - 1) * 8192);
                    #pragma unroll
                    for (int kb = 0; kb < 8; ++kb) {
                        int k = kb * 32 + kh * 8;
                        bf16x8 a0h = *reinterpret_cast<const bf16x8*>(hB + cl * 256 + k);
                        bf16x8 a1h = *reinterpret_cast<const bf16x8*>(hB + (16 + cl) * 256 + k);
                        bf16x8 a0l = *reinterpret_cast<const bf16x8*>(lB + cl * 256 + k);
                        bf16x8 a1l = *reinterpret_cast<const bf16x8*>(lB + (16 + cl) * 256 + k);
                        acc0 = __builtin_amdgcn_mfma_f32_16x16x32_bf16(a0h, wh[kb], acc0, 0, 0, 0);
                        acc0 = __builtin_amdgcn_mfma_f32_16x16x32_bf16(a0l, wh[kb], acc0, 0, 0, 0);
                        acc0 = __builtin_amdgcn_mfma_f32_16x16x32_bf16(a0h, wl[kb], acc0, 0, 0, 0);
                        acc1 = __builtin_amdgcn_mfma_f32_16x16x32_bf16(a1h, wh[kb], acc1, 0, 0, 0);
                        acc1 = __builtin_amdgcn_mfma_f32_16x16x32_bf16(a1l, wh[kb], acc1, 0, 0, 0);
                        acc1 = __builtin_amdgcn_mfma_f32_16x16x32_bf16(a1h, wl[kb], acc1, 0, 0, 0);
                    }
                }
                for (int r = 0; r < 4; ++r) {
                    zbuf[wv][cl][kh * 4 + r] = acc0[r];
                    zbuf[wv][cl][16 + kh * 4 + r] = acc1[r];
                }
                __syncthreads();
                float zi = zbuf[0][dr_r][b_r]     + zbuf[2][dr_r][b_r]     + bias0;
                float zf = zbuf[0][8 + dr_r][b_r] + zbuf[2][8 + dr_r][b_r] + bias1;
                float zg = zbuf[1][dr_r][b_r]     + zbuf[3][dr_r][b_r]     + bias2;
                float zo = zbuf[1][8 + dr_r][b_r] + zbuf[3][8 + dr_r][b_r] + bias3;
                float cn = sigm(zf) * cst0 + sigm(zi) * tanhf(zg);
                float hn = sigm(zo) * tanhf(cn);
                cst0 = cn;
                unsigned short hv = f2bf(hn);
                unsigned short lv = f2bf(hn - bf2f(hv));
                size_t ho = ((size_t)s * 32 + b_r) * 256 + d0 + dr_r;
                h2hi[ho] = hv;
                h2lo[ho] = lv;
            }
        }
        if (p < 64) gridbar(bar, p, tid);
    }
}

// ---------------------------------------------------------------------------
// tail_k: per batch, only row v* = lengths[b]-1 matters. float4 weight reads.
// ---------------------------------------------------------------------------
__global__ void __launch_bounds__(256) tail_k(
    const int* __restrict__ lengths,
    const unsigned short* __restrict__ h1hi, const unsigned short* __restrict__ h1lo,
    const unsigned short* __restrict__ h2hi, const unsigned short* __restrict__ h2lo,
    const float* __restrict__ whk_W, const float* __restrict__ whk_b,
    const float* __restrict__ w1_W, const float* __restrict__ w1_b,
    const float* __restrict__ w2_W, const float* __restrict__ w2_b,
    const float* __restrict__ fuse_W, const float* __restrict__ fuse_b,
    const float* __restrict__ lab_W, const float* __restrict__ lab_b,
    const float* __restrict__ Wdiff, const float* __restrict__ alpha,
    const float* __restrict__ noise, float* __restrict__ out) {
    __shared__ float ek[256], tv[256], hs[256], whp[256], a1s[64];
    __shared__ float noisy_s[256], fin[512], fused_s[256], attn_s[2];
    int b = blockIdx.x, tid = threadIdx.x;
    int vstar = lengths[b] - 1;
    {
        size_t o0 = (size_t)b * 256 + tid;                          // t=0
        size_t ov = ((size_t)vstar * 32 + b) * 256 + tid;
        ek[tid] = bf2f(h1hi[o0]) + bf2f(h1lo[o0]);
        tv[tid] = bf2f(h1hi[ov]) + bf2f(h1lo[ov]);
        if (vstar > 0) {
            size_t oh = ((size_t)(vstar - 1) * 32 + b) * 256 + tid;
            hs[tid] = bf2f(h2hi[oh]) + bf2f(h2lo[oh]);
        }
    }
    __syncthreads();

    float aligned;
    if (vstar > 0) {
        float acc = whk_b[tid];
        const float4* wr4 = reinterpret_cast<const float4*>(whk_W + (size_t)tid * 256);
        #pragma unroll 8
        for (int k4 = 0; k4 < 64; ++k4) {
            float4 w = wr4[k4];
            acc += w.x * hs[k4 * 4] + w.y * hs[k4 * 4 + 1] + w.z * hs[k4 * 4 + 2] + w.w * hs[k4 * 4 + 3];
        }
        whp[tid] = acc;
        __syncthreads();
        if (tid < 64) {
            float a2 = w1_b[tid];
            const float4* wr14 = reinterpret_cast<const float4*>(w1_W + (size_t)tid * 512);
            #pragma unroll 8
            for (int k4 = 0; k4 < 64; ++k4) {
                float4 w = wr14[k4];
                a2 += w.x * ek[k4 * 4] + w.y * ek[k4 * 4 + 1] + w.z * ek[k4 * 4 + 2] + w.w * ek[k4 * 4 + 3];
            }
            #pragma unroll 8
            for (int k4 = 0; k4 < 64; ++k4) {
                float4 w = wr14[64 + k4];
                a2 += w.x * whp[k4 * 4] + w.y * whp[k4 * 4 + 1] + w.z * whp[k4 * 4 + 2] + w.w * whp[k4 * 4 + 3];
            }
            a1s[tid] = tanhf(a2);
        }
        __syncthreads();
        if (tid < 2) {
            float a3 = w2_b[tid];
            const float* wr2 = w2_W + tid * 64;
            for (int k = 0; k < 64; ++k) a3 += wr2[k] * a1s[k];
            attn_s[tid] = a3;
        }
        __syncthreads();
        float m = fmaxf(attn_s[0], attn_s[1]);
        float e0 = __expf(attn_s[0] - m), e1 = __expf(attn_s[1] - m);
        float inv = 1.f / (e0 + e1);
        aligned = ek[tid] * (e0 * inv) + whp[tid] * (e1 * inv);
    } else {
        aligned = ek[tid];
    }

    float al = alpha[b];
    float sa = sqrtf(al), sb = sqrtf(1.f - al);
    float nz = noise[((size_t)b * 64 + vstar) * 256 + tid];
    noisy_s[tid] = aligned * sa + nz * sb;
    __syncthreads();
    float pn = 0.f;
    for (int k = 0; k < 256; ++k) pn += noisy_s[k] * Wdiff[(size_t)k * 256 + tid];
    float gen = aligned + nz - pn;
    fin[tid] = tv[tid];
    fin[256 + tid] = gen;
    __syncthreads();
    float fu = fuse_b[tid];
    const float4* fw4 = reinterpret_cast<const float4*>(fuse_W + (size_t)tid * 512);
    #pragma unroll 8
    for (int k4 = 0; k4 < 128; ++k4) {
        float4 w = fw4[k4];
        fu += w.x * fin[k4 * 4] + w.y * fin[k4 * 4 + 1] + w.z * fin[k4 * 4 + 2] + w.w * fin[k4 * 4 + 3];
    }
    fused_s[tid] = fu;
    __syncthreads();
    if (tid < 2) {
        float o = lab_b[tid];
        const float* lw = lab_W + tid * 256;
        for (int k = 0; k < 256; ++k) o += lw[k] * fused_s[k];
        out[b * 2 + tid] = o;
    }
}

// ---------------------------------------------------------------------------
extern "C" void kernel_launch(void* const* d_in, const int* in_sizes, int n_in,
                              void* d_out, int out_size, void* d_ws, size_t ws_size,
                              hipStream_t stream) {
    const int*   seqs    = (const int*)  d_in[0];
    const int*   lengths = (const int*)  d_in[2];
    const float* tstep   = (const float*)d_in[3];
    const float* cmask   = (const float*)d_in[4];
    const float* emb     = (const float*)d_in[5];
    const float* WQ1     = (const float*)d_in[6];
    const float* WK1     = (const float*)d_in[7];
    const float* decay   = (const float*)d_in[8];
    const float* initial = (const float*)d_in[9];
    const float* Wih1    = (const float*)d_in[10];
    const float* Whh1    = (const float*)d_in[11];
    const float* lstm_b  = (const float*)d_in[12];
    const float* Wih2    = (const float*)d_in[13];
    const float* Whh2    = (const float*)d_in[14];
    const float* hs_b    = (const float*)d_in[15];
    const float* whk_W   = (const float*)d_in[16];
    const float* whk_b   = (const float*)d_in[17];
    const float* w1_W    = (const float*)d_in[18];
    const float* w1_b    = (const float*)d_in[19];
    const float* w2_W    = (const float*)d_in[20];
    const float* w2_b    = (const float*)d_in[21];
    const float* fuse_W  = (const float*)d_in[22];
    const float* fuse_b  = (const float*)d_in[23];
    const float* lab_W   = (const float*)d_in[24];
    const float* lab_b   = (const float*)d_in[25];
    const float* betas   = (const float*)d_in[26];
    const float* Wdiff   = (const float*)d_in[27];
    const int*   dift    = (const int*)  d_in[28];
    const float* noise   = (const float*)d_in[29];
    float* out = (float*)d_out;

    float* ws = (float*)d_ws;
    size_t off = 0;
    auto alloc = [&](size_t nfloats) { size_t r = off; off += (nfloats + 63) & ~(size_t)63; return r; };
    unsigned short* M_pk   = (unsigned short*)(ws + alloc(32768));
    float*          alpha  = ws + alloc(64);
    int*            bar    = (int*)(ws + alloc(128));
    float*          vv     = ws + alloc(524288);
    unsigned short* X1bf   = (unsigned short*)(ws + alloc(1048576));  // 64*1024*32 u16
    unsigned short* h1hi   = (unsigned short*)(ws + alloc(262144));   // 64*32*256 u16
    unsigned short* h1lo   = (unsigned short*)(ws + alloc(262144));
    unsigned short* h2hi   = (unsigned short*)(ws + alloc(262144));
    unsigned short* h2lo   = (unsigned short*)(ws + alloc(262144));
    unsigned short* Wpk_hi = (unsigned short*)(ws + alloc(393216));   // 48*16384 u16
    unsigned short* Wpk_lo = (unsigned short*)(ws + alloc(393216));
    unsigned short* W1h    = (unsigned short*)(ws + alloc(131072));   // 64*8*64*8 u16
    unsigned short* W1l    = (unsigned short*)(ws + alloc(131072));

    prep_M<<<64, 256, 0, stream>>>(WQ1, WK1, M_pk);
    pack_rec<<<385, 256, 0, stream>>>(Whh1, Wih2, Whh2, Wpk_hi, Wpk_lo, bar);
    pack_w1<<<129, 256, 0, stream>>>(Wih1, W1h, W1l, betas, dift, alpha);
    attn_bags<<<2048, 256, 0, stream>>>(seqs, tstep, cmask, emb, decay, initial, M_pk, vv);
    x1_mfma<<<512, 256, 0, stream>>>(vv, W1h, W1l, lstm_b, X1bf);
    lstm_persist<<<NWG_LSTM, 256, 0, stream>>>(Wpk_hi, Wpk_lo, X1bf, hs_b,
                                               h1hi, h1lo, h2hi, h2lo, bar);
    tail_k<<<32, 256, 0, stream>>>(lengths, h1hi, h1lo, h2hi, h2lo, whk_W, whk_b,
                                   w1_W, w1_b, w2_W, w2_b, fuse_W, fuse_b,
                                   lab_W, lab_b, Wdiff, alpha, noise, out);
}

// Round 3
// 499.004 us; speedup vs baseline: 2.4686x; 1.8147x over previous
//
#include <hip/hip_runtime.h>
#include <hip/hip_bf16.h>
#include <cmath>

typedef __attribute__((ext_vector_type(8))) short bf16x8;
typedef __attribute__((ext_vector_type(4))) float f32x4;

#define NWG_LSTM 48

__device__ __forceinline__ float bf2f(unsigned short u) {
    unsigned int x = ((unsigned int)u) << 16;
    return __builtin_bit_cast(float, x);
}
__device__ __forceinline__ unsigned short f2bf(float f) {
    unsigned int x = __builtin_bit_cast(unsigned int, f);
    unsigned int lsb = (x >> 16) & 1u;
    x += 0x7fffu + lsb;
    return (unsigned short)(x >> 16);
}
__device__ __forceinline__ float sigm(float z) {
    return 1.f / (1.f + __expf(-z));
}

// Agent-coherent 16B load: bypasses non-coherent local caches (sc1 -> IF$).
// NOTE: compiler does not know this is a load; caller must s_waitcnt vmcnt(0)
// + sched_barrier(0) before consuming (guide rule #18).
__device__ __forceinline__ bf16x8 ldg_sc(const unsigned short* p) {
    bf16x8 r;
    asm volatile("global_load_dwordx4 %0, %1, off sc1"
                 : "=v"(r) : "v"(p) : "memory");
    return r;
}

// ---------------------------------------------------------------------------
// prep_M: M = WQ1^T @ WK1  (256x256), bf16 in MFMA B-fragment order.
// ---------------------------------------------------------------------------
__global__ void __launch_bounds__(256) prep_M(const float* __restrict__ WQ1,
                                              const float* __restrict__ WK1,
                                              unsigned short* __restrict__ M_pk) {
    __shared__ unsigned short As[256][32];
    __shared__ unsigned short Bs[256][32];
    int bx = blockIdx.x;
    int e0 = (bx >> 3) << 5;
    int f0 = (bx & 7) << 5;
    int tid = threadIdx.x;
    int col = tid & 31, rr = tid >> 5;
    for (int rep = 0; rep < 32; ++rep) {
        int d = rep * 8 + rr;
        As[d][col] = f2bf(WQ1[d * 256 + e0 + col]);
        Bs[d][col] = f2bf(WK1[d * 256 + f0 + col]);
    }
    __syncthreads();
    int el = tid & 31;
    int fl0 = tid >> 5;
    for (int i = 0; i < 4; ++i) {
        int fl = fl0 + 8 * i;
        float acc = 0.f;
        for (int d = 0; d < 256; ++d)
            acc += bf2f(As[d][el]) * bf2f(Bs[d][fl]);
        int e = e0 + el, f = f0 + fl;
        int kb = e >> 5, r = (e >> 3) & 3, j = e & 7;
        int nb = f >> 4;
        int lane = (r << 4) | (f & 15);
        M_pk[(((nb * 8 + kb) * 64) + lane) * 8 + j] = f2bf(acc);
    }
}

// ---------------------------------------------------------------------------
// pack_rec: pack Whh1/Wih2/Whh2 into per-wg bf16 hi/lo fragment streams.
// Block 384 zeroes the per-wave flag array (12288 ints).
// ---------------------------------------------------------------------------
__global__ void __launch_bounds__(256) pack_rec(const float* __restrict__ Whh1,
                                                const float* __restrict__ Wih2,
                                                const float* __restrict__ Whh2,
                                                unsigned short* __restrict__ Wpk_hi,
                                                unsigned short* __restrict__ Wpk_lo,
                                                int* __restrict__ flags) {
    if (blockIdx.x == 384) {
        for (int i = threadIdx.x; i < 12288; i += 256) flags[i] = 0;
        return;
    }
    int c = blockIdx.x * 256 + threadIdx.x;      // chunk id, 98304 total
    int w = c >> 11;
    int r = c & 2047;
    int i = r >> 6;
    int lane = r & 63;
    int cl = lane & 15, kh = lane >> 4;
    const float* src;
    int grow, k0;
    if (w < 16) {
        int d0 = w * 16;
        int nt = i >> 3, kb = i & 7;
        grow = nt * 256 + d0 + cl;
        k0 = kb * 32 + kh * 8;
        src = Whh1;
    } else {
        int d0 = (w - 16) * 8;
        int mat = i >> 4;
        int ii = i & 15;
        int nt2 = ii >> 3, kb = ii & 7;
        grow = (nt2 * 2 + (cl >> 3)) * 256 + d0 + (cl & 7);
        k0 = kb * 32 + kh * 8;
        src = mat ? Whh2 : Wih2;
    }
    const float* sp = src + (size_t)grow * 256 + k0;
    bf16x8 hi, lo;
    for (int j = 0; j < 8; ++j) {
        float v = sp[j];
        unsigned short h = f2bf(v);
        hi[j] = (short)h;
        lo[j] = (short)f2bf(v - bf2f(h));
    }
    size_t o = (size_t)c * 8;
    *reinterpret_cast<bf16x8*>(Wpk_hi + o) = hi;
    *reinterpret_cast<bf16x8*>(Wpk_lo + o) = lo;
}

// ---------------------------------------------------------------------------
// pack_w1: Wih1 -> bf16 hi/lo fragment stream. Block 128: alpha cumprod.
// ---------------------------------------------------------------------------
__global__ void __launch_bounds__(256) pack_w1(const float* __restrict__ Wih1,
                                               unsigned short* __restrict__ W1h,
                                               unsigned short* __restrict__ W1l,
                                               const float* __restrict__ betas,
                                               const int* __restrict__ dift,
                                               float* __restrict__ alpha) {
    if (blockIdx.x == 128) {
        int tid = threadIdx.x;
        if (tid < 32) {
            int tb = dift[tid];
            float p = 1.f;
            for (int i = 0; i <= tb; ++i) p *= (1.f - betas[i]);
            alpha[tid] = p;
        }
        return;
    }
    int c = blockIdx.x * 256 + threadIdx.x;      // 32768 chunks
    int nt = c >> 9;
    int r = c & 511;
    int kb = r >> 6;
    int lane = r & 63;
    int grow = nt * 16 + (lane & 15);
    int k0 = kb * 32 + (lane >> 4) * 8;
    const float* sp = Wih1 + (size_t)grow * 256 + k0;
    bf16x8 hi, lo;
    for (int j = 0; j < 8; ++j) {
        float v = sp[j];
        unsigned short h = f2bf(v);
        hi[j] = (short)h;
        lo[j] = (short)f2bf(v - bf2f(h));
    }
    size_t o = (size_t)c * 8;
    *reinterpret_cast<bf16x8*>(W1h + o) = hi;
    *reinterpret_cast<bf16x8*>(W1l + o) = lo;
}

// ---------------------------------------------------------------------------
// attn_bags (unchanged, verified)
// ---------------------------------------------------------------------------
__global__ void __launch_bounds__(256) attn_bags(
    const int* __restrict__ seqs, const float* __restrict__ tstep,
    const float* __restrict__ cmask, const float* __restrict__ emb,
    const float* __restrict__ decay, const float* __restrict__ initial,
    const unsigned short* __restrict__ M_pk, float* __restrict__ vv) {
    __shared__ __align__(16) unsigned short x_bf[32 * 256];
    __shared__ __align__(16) unsigned short t1_bf[32 * 256];
    __shared__ float dp_f[32 * 33];
    __shared__ float gate_sh[32];
    __shared__ float cm_sh[32];
    __shared__ int tok_sh[32];
    __shared__ float w_sh[32];

    int bag = blockIdx.x;
    int tid = threadIdx.x;

    if (tid < 32) {
        int tok = seqs[bag * 32 + tid];
        tok_sh[tid] = tok;
        float cm = cmask[bag * 32 + tid];
        cm_sh[tid] = cm;
        float tt = tstep[bag];
        float g = sigm(decay[tok] * tt + initial[tok]);
        g *= (cm - 1e20f) / (-1e20f);
        gate_sh[tid] = g;
    }
    __syncthreads();

    for (int it = 0; it < 8; ++it) {
        int fidx = it * 256 + tid;
        int c = fidx >> 6;
        int f4 = fidx & 63;
        const float4* src = reinterpret_cast<const float4*>(emb + (size_t)tok_sh[c] * 256) + f4;
        float4 vx = *src;
        int colx = f4 * 4;
        int eidx = c * 256 + (colx ^ ((c & 7) << 3));
        ushort4 w;
        w.x = f2bf(vx.x); w.y = f2bf(vx.y); w.z = f2bf(vx.z); w.w = f2bf(vx.w);
        *reinterpret_cast<ushort4*>(&x_bf[eidx]) = w;
    }
    __syncthreads();

    int wv = tid >> 6;
    int lane = tid & 63;
    int lr = lane & 15;
    int lk = lane >> 4;

    f32x4 acc[2][4];
    for (int a = 0; a < 2; ++a)
        for (int n = 0; n < 4; ++n) acc[a][n] = (f32x4){0.f, 0.f, 0.f, 0.f};
    for (int kb = 0; kb < 8; ++kb) {
        bf16x8 afr[2];
        for (int mb = 0; mb < 2; ++mb) {
            int row = mb * 16 + lr;
            int colx = kb * 32 + lk * 8;
            afr[mb] = *reinterpret_cast<const bf16x8*>(&x_bf[row * 256 + (colx ^ ((row & 7) << 3))]);
        }
        for (int nbi = 0; nbi < 4; ++nbi) {
            int nb = wv * 4 + nbi;
            bf16x8 bfr = *reinterpret_cast<const bf16x8*>(M_pk + (((nb * 8 + kb) * 64) + lane) * 8);
            acc[0][nbi] = __builtin_amdgcn_mfma_f32_16x16x32_bf16(afr[0], bfr, acc[0][nbi], 0, 0, 0);
            acc[1][nbi] = __builtin_amdgcn_mfma_f32_16x16x32_bf16(afr[1], bfr, acc[1][nbi], 0, 0, 0);
        }
    }
    for (int mb = 0; mb < 2; ++mb)
        for (int nbi = 0; nbi < 4; ++nbi)
            for (int r = 0; r < 4; ++r) {
                int row = mb * 16 + lk * 4 + r;
                int colx = wv * 64 + nbi * 16 + lr;
                t1_bf[row * 256 + (colx ^ ((row & 7) << 3))] = f2bf(acc[mb][nbi][r]);
            }
    __syncthreads();

    {
        int mb = wv >> 1, nb2 = wv & 1;
        f32x4 dacc = (f32x4){0.f, 0.f, 0.f, 0.f};
        for (int kb = 0; kb < 8; ++kb) {
            int cola = kb * 32 + lk * 8;
            int rowa = mb * 16 + lr;
            bf16x8 afr = *reinterpret_cast<const bf16x8*>(&t1_bf[rowa * 256 + (cola ^ ((rowa & 7) << 3))]);
            int rowb = nb2 * 16 + lr;
            bf16x8 bfr = *reinterpret_cast<const bf16x8*>(&x_bf[rowb * 256 + (cola ^ ((rowb & 7) << 3))]);
            dacc = __builtin_amdgcn_mfma_f32_16x16x32_bf16(afr, bfr, dacc, 0, 0, 0);
        }
        for (int r = 0; r < 4; ++r) {
            int c = mb * 16 + lk * 4 + r;
            int e = nb2 * 16 + lr;
            dp_f[c * 33 + e] = dacc[r];
        }
    }
    __syncthreads();

    if (tid < 32) {
        int c = tid;
        float cmc = cm_sh[c];
        float lg[32];
        float mx = -1e30f;
        for (int e = 0; e < 32; ++e) {
            float l = (dp_f[c * 33 + e] - cmc - cm_sh[e]) * 0.0625f;
            lg[e] = l;
            mx = fmaxf(mx, l);
        }
        float s = 0.f;
        for (int e = 0; e < 32; ++e) { float ex = __expf(lg[e] - mx); lg[e] = ex; s += ex; }
        float inv = 1.f / s;
        for (int e = 0; e < 32; ++e) dp_f[c * 33 + e] = lg[e] * inv;
    }
    __syncthreads();
    if (tid < 32) {
        int e = tid;
        float a2 = 0.f;
        for (int c = 0; c < 32; ++c) a2 += gate_sh[c] * dp_f[c * 33 + e];
        w_sh[e] = a2;
    }
    __syncthreads();

    float accv = 0.f;
    int d = tid;
    for (int e = 0; e < 32; ++e)
        accv += w_sh[e] * bf2f(x_bf[e * 256 + (d ^ ((e & 7) << 3))]);
    vv[(size_t)bag * 256 + d] = accv;
}

// ---------------------------------------------------------------------------
// x1_mfma: X1bf[t][g][b] = bf16( vv @ Wih1^T + lstm_b ), split-bf16 MFMA.
// ---------------------------------------------------------------------------
__global__ void __launch_bounds__(256) x1_mfma(const float* __restrict__ vv,
                                               const unsigned short* __restrict__ W1h,
                                               const unsigned short* __restrict__ W1l,
                                               const float* __restrict__ lstm_b,
                                               unsigned short* __restrict__ X1bf) {
    __shared__ __align__(16) unsigned short xs[32 * 256];
    int blk = blockIdx.x;
    int rb = blk >> 3, gb = blk & 7;
    int tid = threadIdx.x;
    for (int it = 0; it < 8; ++it) {
        int idx = it * 256 + tid;
        int row = idx >> 6, f4 = idx & 63;
        float4 v = *reinterpret_cast<const float4*>(vv + (size_t)(rb * 32 + row) * 256 + f4 * 4);
        ushort4 w;
        w.x = f2bf(v.x); w.y = f2bf(v.y); w.z = f2bf(v.z); w.w = f2bf(v.w);
        *reinterpret_cast<ushort4*>(&xs[row * 256 + ((f4 * 4) ^ ((row & 7) << 3))]) = w;
    }
    __syncthreads();
    int wv = tid >> 6, lane = tid & 63, cl = lane & 15, kh = lane >> 4;
    f32x4 acc[2][2];
    for (int n = 0; n < 2; ++n) {
        int nt = gb * 8 + wv * 2 + n;
        float bz = lstm_b[nt * 16 + cl];
        acc[n][0] = (f32x4){bz, bz, bz, bz};
        acc[n][1] = (f32x4){bz, bz, bz, bz};
    }
    #pragma unroll
    for (int kb = 0; kb < 8; ++kb) {
        int k = kb * 32 + kh * 8;
        bf16x8 a0 = *reinterpret_cast<const bf16x8*>(&xs[cl * 256 + (k ^ ((cl & 7) << 3))]);
        bf16x8 a1 = *reinterpret_cast<const bf16x8*>(&xs[(16 + cl) * 256 + (k ^ (((16 + cl) & 7) << 3))]);
        for (int n = 0; n < 2; ++n) {
            int nt = gb * 8 + wv * 2 + n;
            size_t o = ((size_t)(nt * 8 + kb) * 64 + lane) * 8;
            bf16x8 bh = *reinterpret_cast<const bf16x8*>(W1h + o);
            bf16x8 bl = *reinterpret_cast<const bf16x8*>(W1l + o);
            acc[n][0] = __builtin_amdgcn_mfma_f32_16x16x32_bf16(a0, bh, acc[n][0], 0, 0, 0);
            acc[n][0] = __builtin_amdgcn_mfma_f32_16x16x32_bf16(a0, bl, acc[n][0], 0, 0, 0);
            acc[n][1] = __builtin_amdgcn_mfma_f32_16x16x32_bf16(a1, bh, acc[n][1], 0, 0, 0);
            acc[n][1] = __builtin_amdgcn_mfma_f32_16x16x32_bf16(a1, bl, acc[n][1], 0, 0, 0);
        }
    }
    for (int n = 0; n < 2; ++n) {
        int nt = gb * 8 + wv * 2 + n;
        int g = nt * 16 + cl;
        for (int mt = 0; mt < 2; ++mt)
            for (int r = 0; r < 4; ++r) {
                int row = rb * 32 + mt * 16 + kh * 4 + r;
                int b = row >> 6, t = row & 63;
                X1bf[((size_t)t * 1024 + g) * 32 + b] = f2bf(acc[n][mt][r]);
            }
    }
}

// ---------------------------------------------------------------------------
// lstm_persist: flush-free producer/consumer via sc1 (IF$-coherent) accesses.
// wgs 0..15 (A): LSTM1, d-slice 16. wgs 16..47 (B): LSTM2, d-slice 8.
// Per-wave ready flags: flags[step][slot]; slot = wg*4+wv (A: 0..63),
// 64+(wg-16)*4+wv (B: 64..191). h stored bf16 (single plane), [t][b][d].
// Protocol: data stores (relaxed agent atomics, write-through) ->
// s_waitcnt vmcnt(0) -> flag store. Consumer: poll flags -> sc1 loads.
// ---------------------------------------------------------------------------
__global__ void __launch_bounds__(256, 1) lstm_persist(
    const unsigned short* __restrict__ Wpk_hi, const unsigned short* __restrict__ Wpk_lo,
    const unsigned short* __restrict__ X1bf, const float* __restrict__ hs_b,
    unsigned short* h1, unsigned short* h2, int* flags) {
    __shared__ float zbuf[4][16][33];
    int wg = blockIdx.x, tid = threadIdx.x;
    int wv = tid >> 6, lane = tid & 63, cl = lane & 15, kh = lane >> 4;
    bool isA = wg < 16;
    int d0 = isA ? wg * 16 : (wg - 16) * 8;

    bf16x8 wh[8], wl[8];
    #pragma unroll
    for (int kb = 0; kb < 8; ++kb) {
        size_t o = ((size_t)(wg * 32 + wv * 8 + kb) * 64 + lane) * 8;
        wh[kb] = *reinterpret_cast<const bf16x8*>(Wpk_hi + o);
        wl[kb] = *reinterpret_cast<const bf16x8*>(Wpk_lo + o);
    }

    if (isA) {
        int q = tid & 7, b_r = tid >> 3;
        int slot = wg * 4 + wv;
        float cst[2] = {0.f, 0.f};
        for (int p = 0; p < 64; ++p) {
            f32x4 p0h = (f32x4){0.f,0.f,0.f,0.f}, p0l = p0h, p1h = p0h, p1l = p0h;
            if (p > 0) {
                // poll previous-step A flags (all waves, one word per lane)
                const int* f = flags + (p - 1) * 192;
                while (1) {
                    int v = __hip_atomic_load(f + lane, __ATOMIC_RELAXED, __HIP_MEMORY_SCOPE_AGENT);
                    if (__all(v != 0)) break;
                    __builtin_amdgcn_s_sleep(1);
                }
                __builtin_amdgcn_sched_barrier(0);
                const unsigned short* hB = h1 + (size_t)(p - 1) * 8192;
                bf16x8 a0[8], a1[8];
                #pragma unroll
                for (int kb = 0; kb < 8; ++kb) {
                    a0[kb] = ldg_sc(hB + cl * 256 + kb * 32 + kh * 8);
                    a1[kb] = ldg_sc(hB + (16 + cl) * 256 + kb * 32 + kh * 8);
                }
                asm volatile("s_waitcnt vmcnt(0)" ::: "memory");
                __builtin_amdgcn_sched_barrier(0);
                #pragma unroll
                for (int kb = 0; kb < 8; ++kb) {
                    p0h = __builtin_amdgcn_mfma_f32_16x16x32_bf16(a0[kb], wh[kb], p0h, 0, 0, 0);
                    p0l = __builtin_amdgcn_mfma_f32_16x16x32_bf16(a0[kb], wl[kb], p0l, 0, 0, 0);
                    p1h = __builtin_amdgcn_mfma_f32_16x16x32_bf16(a1[kb], wh[kb], p1h, 0, 0, 0);
                    p1l = __builtin_amdgcn_mfma_f32_16x16x32_bf16(a1[kb], wl[kb], p1l, 0, 0, 0);
                }
            }
            __syncthreads();   // previous zbuf fully consumed
            #pragma unroll
            for (int r = 0; r < 4; ++r) {
                zbuf[wv][cl][kh * 4 + r] = p0h[r] + p0l[r];
                zbuf[wv][cl][16 + kh * 4 + r] = p1h[r] + p1l[r];
            }
            __syncthreads();
            unsigned short hv[2];
            #pragma unroll
            for (int dd = 0; dd < 2; ++dd) {
                int dl = 2 * q + dd;
                size_t xb = ((size_t)p * 1024 + d0 + dl) * 32 + b_r;
                float zi = zbuf[0][dl][b_r] + bf2f(X1bf[xb]);
                float zf = zbuf[1][dl][b_r] + bf2f(X1bf[xb + 8192]);
                float zg = zbuf[2][dl][b_r] + bf2f(X1bf[xb + 16384]);
                float zo = zbuf[3][dl][b_r] + bf2f(X1bf[xb + 24576]);
                float cn = sigm(zf) * cst[dd] + sigm(zi) * tanhf(zg);
                float hn = sigm(zo) * tanhf(cn);
                cst[dd] = cn;
                hv[dd] = f2bf(hn);
            }
            unsigned int val = (unsigned int)hv[0] | ((unsigned int)hv[1] << 16);
            __hip_atomic_store((unsigned int*)h1 + ((size_t)(p * 32 + b_r) * 128 + (d0 >> 1) + q),
                               val, __ATOMIC_RELAXED, __HIP_MEMORY_SCOPE_AGENT);
            asm volatile("s_waitcnt vmcnt(0)" ::: "memory");   // wave's h stores at IF$
            if (lane == 0)
                __hip_atomic_store(flags + p * 192 + slot, 1,
                                   __ATOMIC_RELAXED, __HIP_MEMORY_SCOPE_AGENT);
        }
    } else {
        int q = tid & 3, b_r = tid >> 2;   // valid for tid<128
        int slot = 64 + (wg - 16) * 4 + wv;
        int mat = wv >> 1;
        float cst[2] = {0.f, 0.f};
        float bias[4][2];
        if (tid < 128)
            for (int g = 0; g < 4; ++g)
                for (int dd = 0; dd < 2; ++dd)
                    bias[g][dd] = hs_b[g * 256 + d0 + 2 * q + dd];
        for (int p = 1; p <= 64; ++p) {
            int s = p - 1;
            {   // poll: A flags at s; B flags at s-1 (if s>0)
                const int* fA = flags + s * 192;
                const int* fB = flags + (s - 1) * 192;
                while (1) {
                    int va = __hip_atomic_load(fA + lane, __ATOMIC_RELAXED, __HIP_MEMORY_SCOPE_AGENT);
                    int ok = (va != 0);
                    if (s > 0) {
                        int v1 = __hip_atomic_load(fB + 64 + lane, __ATOMIC_RELAXED, __HIP_MEMORY_SCOPE_AGENT);
                        int v2 = __hip_atomic_load(fB + 128 + lane, __ATOMIC_RELAXED, __HIP_MEMORY_SCOPE_AGENT);
                        ok = ok && (v1 != 0) && (v2 != 0);
                    }
                    if (__all(ok)) break;
                    __builtin_amdgcn_s_sleep(1);
                }
                __builtin_amdgcn_sched_barrier(0);
            }
            f32x4 p0h = (f32x4){0.f,0.f,0.f,0.f}, p0l = p0h, p1h = p0h, p1l = p0h;
            bool active = (mat == 0) || (s > 0);
            if (active) {
                const unsigned short* hB =
                    (mat == 0) ? (h1 + (size_t)s * 8192) : (h2 + (size_t)(s - 1) * 8192);
                bf16x8 a0[8], a1[8];
                #pragma unroll
                for (int kb = 0; kb < 8; ++kb) {
                    a0[kb] = ldg_sc(hB + cl * 256 + kb * 32 + kh * 8);
                    a1[kb] = ldg_sc(hB + (16 + cl) * 256 + kb * 32 + kh * 8);
                }
                asm volatile("s_waitcnt vmcnt(0)" ::: "memory");
                __builtin_amdgcn_sched_barrier(0);
                #pragma unroll
                for (int kb = 0; kb < 8; ++kb) {
                    p0h = __builtin_amdgcn_mfma_f32_16x16x32_bf16(a0[kb], wh[kb], p0h, 0, 0, 0);
                    p0l = __builtin_amdgcn_mfma_f32_16x16x32_bf16(a0[kb], wl[kb], p0l, 0, 0, 0);
                    p1h = __builtin_amdgcn_mfma_f32_16x16x32_bf16(a1[kb], wh[kb], p1h, 0, 0, 0);
                    p1l = __builtin_amdgcn_mfma_f32_16x16x32_bf16(a1[kb], wl[kb], p1l, 0, 0, 0);
                }
            }
            __syncthreads();
            #pragma unroll
            for (int r = 0; r < 4; ++r) {
                zbuf[wv][cl][kh * 4 + r] = p0h[r] + p0l[r];
                zbuf[wv][cl][16 + kh * 4 + r] = p1h[r] + p1l[r];
            }
            __syncthreads();
            if (tid < 128) {
                unsigned short hv[2];
                #pragma unroll
                for (int dd = 0; dd < 2; ++dd) {
                    int dl = 2 * q + dd;
                    float zi = zbuf[0][dl][b_r]     + zbuf[2][dl][b_r]     + bias[0][dd];
                    float zf = zbuf[0][8 + dl][b_r] + zbuf[2][8 + dl][b_r] + bias[1][dd];
                    float zg = zbuf[1][dl][b_r]     + zbuf[3][dl][b_r]     + bias[2][dd];
                    float zo = zbuf[1][8 + dl][b_r] + zbuf[3][8 + dl][b_r] + bias[3][dd];
                    float cn = sigm(zf) * cst[dd] + sigm(zi) * tanhf(zg);
                    float hn = sigm(zo) * tanhf(cn);
                    cst[dd] = cn;
                    hv[dd] = f2bf(hn);
                }
                unsigned int val = (unsigned int)hv[0] | ((unsigned int)hv[1] << 16);
                __hip_atomic_store((unsigned int*)h2 + ((size_t)(s * 32 + b_r) * 128 + (d0 >> 1) + q),
                                   val, __ATOMIC_RELAXED, __HIP_MEMORY_SCOPE_AGENT);
            }
            asm volatile("s_waitcnt vmcnt(0)" ::: "memory");
            if (lane == 0)
                __hip_atomic_store(flags + s * 192 + slot, 1,
                                   __ATOMIC_RELAXED, __HIP_MEMORY_SCOPE_AGENT);
        }
    }
}

// ---------------------------------------------------------------------------
// tail_k: per batch, only row v* = lengths[b]-1 matters.
// ---------------------------------------------------------------------------
__global__ void __launch_bounds__(256) tail_k(
    const int* __restrict__ lengths,
    const unsigned short* __restrict__ h1, const unsigned short* __restrict__ h2,
    const float* __restrict__ whk_W, const float* __restrict__ whk_b,
    const float* __restrict__ w1_W, const float* __restrict__ w1_b,
    const float* __restrict__ w2_W, const float* __restrict__ w2_b,
    const float* __restrict__ fuse_W, const float* __restrict__ fuse_b,
    const float* __restrict__ lab_W, const float* __restrict__ lab_b,
    const float* __restrict__ Wdiff, const float* __restrict__ alpha,
    const float* __restrict__ noise, float* __restrict__ out) {
    __shared__ float ek[256], tv[256], hs[256], whp[256], a1s[64];
    __shared__ float noisy_s[256], fin[512], fused_s[256], attn_s[2];
    int b = blockIdx.x, tid = threadIdx.x;
    int vstar = lengths[b] - 1;
    {
        ek[tid] = bf2f(h1[(size_t)b * 256 + tid]);
        tv[tid] = bf2f(h1[((size_t)vstar * 32 + b) * 256 + tid]);
        if (vstar > 0)
            hs[tid] = bf2f(h2[((size_t)(vstar - 1) * 32 + b) * 256 + tid]);
    }
    __syncthreads();

    float aligned;
    if (vstar > 0) {
        float acc = whk_b[tid];
        const float4* wr4 = reinterpret_cast<const float4*>(whk_W + (size_t)tid * 256);
        #pragma unroll 8
        for (int k4 = 0; k4 < 64; ++k4) {
            float4 w = wr4[k4];
            acc += w.x * hs[k4 * 4] + w.y * hs[k4 * 4 + 1] + w.z * hs[k4 * 4 + 2] + w.w * hs[k4 * 4 + 3];
        }
        whp[tid] = acc;
        __syncthreads();
        if (tid < 64) {
            float a2 = w1_b[tid];
            const float4* wr14 = reinterpret_cast<const float4*>(w1_W + (size_t)tid * 512);
            #pragma unroll 8
            for (int k4 = 0; k4 < 64; ++k4) {
                float4 w = wr14[k4];
                a2 += w.x * ek[k4 * 4] + w.y * ek[k4 * 4 + 1] + w.z * ek[k4 * 4 + 2] + w.w * ek[k4 * 4 + 3];
            }
            #pragma unroll 8
            for (int k4 = 0; k4 < 64; ++k4) {
                float4 w = wr14[64 + k4];
                a2 += w.x * whp[k4 * 4] + w.y * whp[k4 * 4 + 1] + w.z * whp[k4 * 4 + 2] + w.w * whp[k4 * 4 + 3];
            }
            a1s[tid] = tanhf(a2);
        }
        __syncthreads();
        if (tid < 2) {
            float a3 = w2_b[tid];
            const float* wr2 = w2_W + tid * 64;
            for (int k = 0; k < 64; ++k) a3 += wr2[k] * a1s[k];
            attn_s[tid] = a3;
        }
        __syncthreads();
        float m = fmaxf(attn_s[0], attn_s[1]);
        float e0 = __expf(attn_s[0] - m), e1 = __expf(attn_s[1] - m);
        float inv = 1.f / (e0 + e1);
        aligned = ek[tid] * (e0 * inv) + whp[tid] * (e1 * inv);
    } else {
        aligned = ek[tid];
    }

    float al = alpha[b];
    float sa = sqrtf(al), sb = sqrtf(1.f - al);
    float nz = noise[((size_t)b * 64 + vstar) * 256 + tid];
    noisy_s[tid] = aligned * sa + nz * sb;
    __syncthreads();
    float pn = 0.f;
    for (int k = 0; k < 256; ++k) pn += noisy_s[k] * Wdiff[(size_t)k * 256 + tid];
    float gen = aligned + nz - pn;
    fin[tid] = tv[tid];
    fin[256 + tid] = gen;
    __syncthreads();
    float fu = fuse_b[tid];
    const float4* fw4 = reinterpret_cast<const float4*>(fuse_W + (size_t)tid * 512);
    #pragma unroll 8
    for (int k4 = 0; k4 < 128; ++k4) {
        float4 w = fw4[k4];
        fu += w.x * fin[k4 * 4] + w.y * fin[k4 * 4 + 1] + w.z * fin[k4 * 4 + 2] + w.w * fin[k4 * 4 + 3];
    }
    fused_s[tid] = fu;
    __syncthreads();
    if (tid < 2) {
        float o = lab_b[tid];
        const float* lw = lab_W + tid * 256;
        for (int k = 0; k < 256; ++k) o += lw[k] * fused_s[k];
        out[b * 2 + tid] = o;
    }
}

// ---------------------------------------------------------------------------
extern "C" void kernel_launch(void* const* d_in, const int* in_sizes, int n_in,
                              void* d_out, int out_size, void* d_ws, size_t ws_size,
                              hipStream_t stream) {
    const int*   seqs    = (const int*)  d_in[0];
    const int*   lengths = (const int*)  d_in[2];
    const float* tstep   = (const float*)d_in[3];
    const float* cmask   = (const float*)d_in[4];
    const float* emb     = (const float*)d_in[5];
    const float* WQ1     = (const float*)d_in[6];
    const float* WK1     = (const float*)d_in[7];
    const float* decay   = (const float*)d_in[8];
    const float* initial = (const float*)d_in[9];
    const float* Wih1    = (const float*)d_in[10];
    const float* Whh1    = (const float*)d_in[11];
    const float* lstm_b  = (const float*)d_in[12];
    const float* Wih2    = (const float*)d_in[13];
    const float* Whh2    = (const float*)d_in[14];
    const float* hs_b    = (const float*)d_in[15];
    const float* whk_W   = (const float*)d_in[16];
    const float* whk_b   = (const float*)d_in[17];
    const float* w1_W    = (const float*)d_in[18];
    const float* w1_b    = (const float*)d_in[19];
    const float* w2_W    = (const float*)d_in[20];
    const float* w2_b    = (const float*)d_in[21];
    const float* fuse_W  = (const float*)d_in[22];
    const float* fuse_b  = (const float*)d_in[23];
    const float* lab_W   = (const float*)d_in[24];
    const float* lab_b   = (const float*)d_in[25];
    const float* betas   = (const float*)d_in[26];
    const float* Wdiff   = (const float*)d_in[27];
    const int*   dift    = (const int*)  d_in[28];
    const float* noise   = (const float*)d_in[29];
    float* out = (float*)d_out;

    float* ws = (float*)d_ws;
    size_t off = 0;
    auto alloc = [&](size_t nfloats) { size_t r = off; off += (nfloats + 63) & ~(size_t)63; return r; };
    unsigned short* M_pk   = (unsigned short*)(ws + alloc(32768));
    float*          alpha  = ws + alloc(64);
    int*            flags  = (int*)(ws + alloc(3072));                // 12288 ints
    float*          vv     = ws + alloc(524288);
    unsigned short* X1bf   = (unsigned short*)(ws + alloc(1048576));  // 64*1024*32 u16
    unsigned short* h1     = (unsigned short*)(ws + alloc(131072));   // 64*32*256 u16
    unsigned short* h2     = (unsigned short*)(ws + alloc(131072));
    unsigned short* Wpk_hi = (unsigned short*)(ws + alloc(393216));   // 48*16384 u16
    unsigned short* Wpk_lo = (unsigned short*)(ws + alloc(393216));
    unsigned short* W1h    = (unsigned short*)(ws + alloc(131072));
    unsigned short* W1l    = (unsigned short*)(ws + alloc(131072));

    prep_M<<<64, 256, 0, stream>>>(WQ1, WK1, M_pk);
    pack_rec<<<385, 256, 0, stream>>>(Whh1, Wih2, Whh2, Wpk_hi, Wpk_lo, flags);
    pack_w1<<<129, 256, 0, stream>>>(Wih1, W1h, W1l, betas, dift, alpha);
    attn_bags<<<2048, 256, 0, stream>>>(seqs, tstep, cmask, emb, decay, initial, M_pk, vv);
    x1_mfma<<<512, 256, 0, stream>>>(vv, W1h, W1l, lstm_b, X1bf);
    lstm_persist<<<NWG_LSTM, 256, 0, stream>>>(Wpk_hi, Wpk_lo, X1bf, hs_b, h1, h2, flags);
    tail_k<<<32, 256, 0, stream>>>(lengths, h1, h2, whk_W, whk_b,
                                   w1_W, w1_b, w2_W, w2_b, fuse_W, fuse_b,
                                   lab_W, lab_b, Wdiff, alpha, noise, out);
}